// Round 2
// baseline (2679.355 us; speedup 1.0000x reference)
//
#include <hip/hip_runtime.h>
#include <hip/hip_bf16.h>

#define LEAKY 0.2f

static inline int ceil_div(int a, int b) { return (a + b - 1) / b; }

// ---------------- CSR build ----------------

__global__ __launch_bounds__(256) void count_kernel(const int* __restrict__ dst,
                                                    int* __restrict__ counts, int E) {
    int i = blockIdx.x * 256 + threadIdx.x;
    if (i < E) atomicAdd(&counts[dst[i]], 1);
}

// tile = 1024 elements per block (256 threads x 4)
__global__ __launch_bounds__(256) void scan_phase1(const int* __restrict__ counts,
                                                   int* __restrict__ rowstart,
                                                   int* __restrict__ tilesums, int n) {
    __shared__ int sdata[256];
    int t = threadIdx.x;
    int base = blockIdx.x * 1024 + t * 4;
    int v[4];
    int s = 0;
#pragma unroll
    for (int j = 0; j < 4; ++j) {
        int idx = base + j;
        v[j] = (idx < n) ? counts[idx] : 0;
        s += v[j];
    }
    sdata[t] = s;
    __syncthreads();
    for (int off = 1; off < 256; off <<= 1) {
        int x = (t >= off) ? sdata[t - off] : 0;
        __syncthreads();
        sdata[t] += x;
        __syncthreads();
    }
    int excl = sdata[t] - s;
    if (t == 255) tilesums[blockIdx.x] = sdata[255];
    int run = excl;
#pragma unroll
    for (int j = 0; j < 4; ++j) {
        int idx = base + j;
        if (idx < n) rowstart[idx] = run;
        run += v[j];
    }
}

__global__ __launch_bounds__(256) void scan_phase2(int* __restrict__ tilesums, int nt) {
    __shared__ int sdata[256];
    int t = threadIdx.x;
    int v = (t < nt) ? tilesums[t] : 0;
    sdata[t] = v;
    __syncthreads();
    for (int off = 1; off < 256; off <<= 1) {
        int x = (t >= off) ? sdata[t - off] : 0;
        __syncthreads();
        sdata[t] += x;
        __syncthreads();
    }
    if (t < nt) tilesums[t] = sdata[t] - v;
}

__global__ __launch_bounds__(256) void scan_phase3(int* __restrict__ rowstart,
                                                   const int* __restrict__ tileoffs,
                                                   int n, int total) {
    int add = tileoffs[blockIdx.x];
    int base = blockIdx.x * 1024 + threadIdx.x * 4;
#pragma unroll
    for (int j = 0; j < 4; ++j) {
        int idx = base + j;
        if (idx < n) rowstart[idx] += add;
    }
    if (blockIdx.x == 0 && threadIdx.x == 0) rowstart[n] = total;
}

__global__ __launch_bounds__(256) void scatter_kernel(const int* __restrict__ src,
                                                      const int* __restrict__ dst,
                                                      const int* __restrict__ rowstart,
                                                      int* __restrict__ cursor,
                                                      int* __restrict__ bucket, int E) {
    int i = blockIdx.x * 256 + threadIdx.x;
    if (i < E) {
        int d = dst[i];
        int p = atomicAdd(&cursor[d], 1);
        bucket[rowstart[d] + p] = src[i];
    }
}

// ---------------- GEMM + attention coefficients ----------------
// feat (bf16) [N][128]; el/er f32 [N][8] computed from f32 accumulators.
__global__ __launch_bounds__(256) void gemm_attn(const float* __restrict__ in,
                                                 const float* __restrict__ W,
                                                 const float* __restrict__ al,
                                                 const float* __restrict__ ar,
                                                 __hip_bfloat16* __restrict__ feat,
                                                 float* __restrict__ el,
                                                 float* __restrict__ er, int N) {
    __shared__ float sIn[32][128];
    int tid = threadIdx.x;
    int c = tid & 127;
    int rgroup = tid >> 7;  // 0 or 1
    int blockrow = blockIdx.x * 32;

    for (int i = tid; i < 32 * 128; i += 256) {
        int r = i >> 7;
        int row = blockrow + r;
        sIn[r][i & 127] = (row < N) ? in[row * 128 + (i & 127)] : 0.0f;
    }
    __syncthreads();

    float acc[16];
#pragma unroll
    for (int r = 0; r < 16; ++r) acc[r] = 0.0f;
    int r0 = rgroup * 16;

    for (int k = 0; k < 128; k += 4) {
        float w0 = W[(k + 0) * 128 + c];
        float w1 = W[(k + 1) * 128 + c];
        float w2 = W[(k + 2) * 128 + c];
        float w3 = W[(k + 3) * 128 + c];
#pragma unroll
        for (int r = 0; r < 16; ++r) {
            float4 f = *reinterpret_cast<const float4*>(&sIn[r0 + r][k]);  // wave-uniform broadcast
            acc[r] += f.x * w0 + f.y * w1 + f.z * w2 + f.w * w3;
        }
    }

    int h = c >> 4;
    int d = c & 15;
    float alv = al[c];
    float arv = ar[c];
#pragma unroll
    for (int r = 0; r < 16; ++r) {
        int row = blockrow + r0 + r;
        if (row < N) {  // wave-uniform branch
            feat[row * 128 + c] = __float2bfloat16(acc[r]);
            float pl = acc[r] * alv;
            float pr = acc[r] * arv;
#pragma unroll
            for (int off = 8; off; off >>= 1) {
                pl += __shfl_xor(pl, off);
                pr += __shfl_xor(pr, off);
            }
            if (d == 0) {
                el[row * 8 + h] = pl;
                er[row * 8 + h] = pr;
            }
        }
    }
}

// ---------------- per-dst-node softmax + aggregation (atomic-free) ----------------
// one wave per node; lane owns components 2*lane, 2*lane+1; head h = lane>>3.
// Edge ids loaded coalesced (lane l loads bucket[beg+l]) and distributed via __shfl;
// edge loop processed in batches of 4 so 8 gathers are in flight per wait.
__global__ __launch_bounds__(256) void aggregate(const ushort* __restrict__ feat,  // bf16 bits
                                                 const float* __restrict__ el,
                                                 const float* __restrict__ er,
                                                 const int* __restrict__ rowstart,
                                                 const int* __restrict__ bucket,
                                                 const float* __restrict__ bias,
                                                 float* __restrict__ out,
                                                 float* __restrict__ mean_out,
                                                 int N, int do_relu) {
    int wid = (blockIdx.x * 256 + threadIdx.x) >> 6;
    int lane = threadIdx.x & 63;
    if (wid >= N) return;
    int h = lane >> 3;
    float er_h = er[wid * 8 + h];
    int beg = rowstart[wid];
    int end = rowstart[wid + 1];

    // lane's two feature components are the uint32 at index (s*64 + lane)
    const unsigned int* fp = reinterpret_cast<const unsigned int*>(feat) + lane;

    float l = 0.0f, ax = 0.0f, ay = 0.0f;

    for (int base = beg; base < end; base += 64) {
        int cnt = min(end - base, 64);
        int myedge = base + lane;
        int sv = (myedge < end) ? bucket[myedge] : 0;  // one coalesced load per 64 edges
        int k = 0;
        for (; k + 4 <= cnt; k += 4) {
            int s0 = __shfl(sv, k + 0);
            int s1 = __shfl(sv, k + 1);
            int s2 = __shfl(sv, k + 2);
            int s3 = __shfl(sv, k + 3);
            float e0 = el[s0 * 8 + h];
            float e1 = el[s1 * 8 + h];
            float e2 = el[s2 * 8 + h];
            float e3 = el[s3 * 8 + h];
            unsigned int u0 = fp[s0 * 64];
            unsigned int u1 = fp[s1 * 64];
            unsigned int u2 = fp[s2 * 64];
            unsigned int u3 = fp[s3 * 64];
            e0 += er_h; e1 += er_h; e2 += er_h; e3 += er_h;
            e0 = (e0 > 0.0f) ? e0 : LEAKY * e0;
            e1 = (e1 > 0.0f) ? e1 : LEAKY * e1;
            e2 = (e2 > 0.0f) ? e2 : LEAKY * e2;
            e3 = (e3 > 0.0f) ? e3 : LEAKY * e3;
            float p0 = __expf(e0), p1 = __expf(e1), p2 = __expf(e2), p3 = __expf(e3);
            l += (p0 + p1) + (p2 + p3);
            ax = fmaf(p0, __uint_as_float(u0 << 16), ax);
            ay = fmaf(p0, __uint_as_float(u0 & 0xffff0000u), ay);
            ax = fmaf(p1, __uint_as_float(u1 << 16), ax);
            ay = fmaf(p1, __uint_as_float(u1 & 0xffff0000u), ay);
            ax = fmaf(p2, __uint_as_float(u2 << 16), ax);
            ay = fmaf(p2, __uint_as_float(u2 & 0xffff0000u), ay);
            ax = fmaf(p3, __uint_as_float(u3 << 16), ax);
            ay = fmaf(p3, __uint_as_float(u3 & 0xffff0000u), ay);
        }
        for (; k < cnt; ++k) {
            int s = __shfl(sv, k);
            float e = el[s * 8 + h] + er_h;
            e = (e > 0.0f) ? e : LEAKY * e;
            float p = __expf(e);
            unsigned int u = fp[s * 64];
            l += p;
            ax = fmaf(p, __uint_as_float(u << 16), ax);
            ay = fmaf(p, __uint_as_float(u & 0xffff0000u), ay);
        }
    }

    float inv = (end > beg) ? 1.0f / l : 0.0f;
    int c = lane * 2;
    float2 bv = *reinterpret_cast<const float2*>(bias + c);
    float ox = fmaf(ax, inv, bv.x);
    float oy = fmaf(ay, inv, bv.y);
    if (do_relu) {
        ox = fmaxf(ox, 0.0f);
        oy = fmaxf(oy, 0.0f);
    }
    if (mean_out) {
        atomicAdd(&mean_out[c], ox);
        atomicAdd(&mean_out[c + 1], oy);
    } else {
        float2 o = {ox, oy};
        *reinterpret_cast<float2*>(out + wid * 128 + c) = o;
    }
}

// ---------------- readout ----------------

__global__ __launch_bounds__(64) void classifier(const float* __restrict__ meanbuf,
                                                 const float* __restrict__ Wc,
                                                 const float* __restrict__ bc,
                                                 float* __restrict__ outp, float invN) {
    int j = threadIdx.x;
    if (j < 10) {
        float s = 0.0f;
        for (int k = 0; k < 128; ++k) s += meanbuf[k] * invN * Wc[k * 10 + j];
        outp[j] = s + bc[j];
    }
}

// ---------------- launch ----------------

extern "C" void kernel_launch(void* const* d_in, const int* in_sizes, int n_in,
                              void* d_out, int out_size, void* d_ws, size_t ws_size,
                              hipStream_t stream) {
    const float* x   = (const float*)d_in[0];
    const int*   src = (const int*)d_in[1];
    const int*   dst = (const int*)d_in[2];
    const float* W1  = (const float*)d_in[3];
    const float* al1 = (const float*)d_in[4];
    const float* ar1 = (const float*)d_in[5];
    const float* b1  = (const float*)d_in[6];
    const float* W2  = (const float*)d_in[7];
    const float* al2 = (const float*)d_in[8];
    const float* ar2 = (const float*)d_in[9];
    const float* b2  = (const float*)d_in[10];
    const float* Wc  = (const float*)d_in[11];
    const float* bc  = (const float*)d_in[12];

    int N = in_sizes[0] / 128;
    int E = in_sizes[1];

    size_t off = 0;
    auto alloc = [&](size_t bytes) -> void* {
        void* p = (char*)d_ws + off;
        off += (bytes + 255) & ~size_t(255);
        return p;
    };
    int*   counts   = (int*)alloc(sizeof(int) * N);
    int*   rowstart = (int*)alloc(sizeof(int) * (N + 1));
    int*   cursor   = (int*)alloc(sizeof(int) * N);
    int*   tilesums = (int*)alloc(sizeof(int) * 256);
    int*   bucket   = (int*)alloc(sizeof(int) * E);
    __hip_bfloat16* feat = (__hip_bfloat16*)alloc(sizeof(__hip_bfloat16) * (size_t)N * 128);
    float* el       = (float*)alloc(sizeof(float) * N * 8);
    float* er       = (float*)alloc(sizeof(float) * N * 8);
    float* h1       = (float*)alloc(sizeof(float) * (size_t)N * 128);
    float* meanbuf  = (float*)alloc(sizeof(float) * 128);

    hipMemsetAsync(counts, 0, sizeof(int) * N, stream);
    hipMemsetAsync(cursor, 0, sizeof(int) * N, stream);
    hipMemsetAsync(meanbuf, 0, sizeof(float) * 128, stream);

    int numTiles = (N + 1023) / 1024;

    count_kernel<<<ceil_div(E, 256), 256, 0, stream>>>(dst, counts, E);
    scan_phase1<<<numTiles, 256, 0, stream>>>(counts, rowstart, tilesums, N);
    scan_phase2<<<1, 256, 0, stream>>>(tilesums, numTiles);
    scan_phase3<<<numTiles, 256, 0, stream>>>(rowstart, tilesums, N, E);
    scatter_kernel<<<ceil_div(E, 256), 256, 0, stream>>>(src, dst, rowstart, cursor, bucket, E);

    // layer 1
    gemm_attn<<<ceil_div(N, 32), 256, 0, stream>>>(x, W1, al1, ar1, feat, el, er, N);
    aggregate<<<ceil_div(N * 64, 256), 256, 0, stream>>>((const ushort*)feat, el, er, rowstart,
                                                         bucket, b1, h1, nullptr, N, 1);
    // layer 2
    gemm_attn<<<ceil_div(N, 32), 256, 0, stream>>>(h1, W2, al2, ar2, feat, el, er, N);
    aggregate<<<ceil_div(N * 64, 256), 256, 0, stream>>>((const ushort*)feat, el, er, rowstart,
                                                         bucket, b2, nullptr, meanbuf, N, 0);
    // readout
    classifier<<<1, 64, 0, stream>>>(meanbuf, Wc, bc, (float*)d_out, 1.0f / (float)N);
}

// Round 3
// 334.347 us; speedup vs baseline: 8.0137x; 8.0137x over previous
//
#include <hip/hip_runtime.h>
#include <hip/hip_bf16.h>

#define LEAKY 0.2f

static inline int ceil_div(int a, int b) { return (a + b - 1) / b; }

// ---------------- CSR build ----------------

__global__ __launch_bounds__(256) void count_kernel(const int* __restrict__ dst,
                                                    int* __restrict__ counts, int E) {
    int i = blockIdx.x * 256 + threadIdx.x;
    if (i < E) atomicAdd(&counts[dst[i]], 1);
}

// tile = 1024 elements per block (256 threads x 4)
__global__ __launch_bounds__(256) void scan_phase1(const int* __restrict__ counts,
                                                   int* __restrict__ rowstart,
                                                   int* __restrict__ tilesums, int n) {
    __shared__ int sdata[256];
    int t = threadIdx.x;
    int base = blockIdx.x * 1024 + t * 4;
    int v[4];
    int s = 0;
#pragma unroll
    for (int j = 0; j < 4; ++j) {
        int idx = base + j;
        v[j] = (idx < n) ? counts[idx] : 0;
        s += v[j];
    }
    sdata[t] = s;
    __syncthreads();
    for (int off = 1; off < 256; off <<= 1) {
        int x = (t >= off) ? sdata[t - off] : 0;
        __syncthreads();
        sdata[t] += x;
        __syncthreads();
    }
    int excl = sdata[t] - s;
    if (t == 255) tilesums[blockIdx.x] = sdata[255];
    int run = excl;
#pragma unroll
    for (int j = 0; j < 4; ++j) {
        int idx = base + j;
        if (idx < n) rowstart[idx] = run;
        run += v[j];
    }
}

__global__ __launch_bounds__(256) void scan_phase2(int* __restrict__ tilesums, int nt) {
    __shared__ int sdata[256];
    int t = threadIdx.x;
    int v = (t < nt) ? tilesums[t] : 0;
    sdata[t] = v;
    __syncthreads();
    for (int off = 1; off < 256; off <<= 1) {
        int x = (t >= off) ? sdata[t - off] : 0;
        __syncthreads();
        sdata[t] += x;
        __syncthreads();
    }
    if (t < nt) tilesums[t] = sdata[t] - v;
}

__global__ __launch_bounds__(256) void scan_phase3(int* __restrict__ rowstart,
                                                   const int* __restrict__ tileoffs,
                                                   int n, int total) {
    int add = tileoffs[blockIdx.x];
    int base = blockIdx.x * 1024 + threadIdx.x * 4;
#pragma unroll
    for (int j = 0; j < 4; ++j) {
        int idx = base + j;
        if (idx < n) rowstart[idx] += add;
    }
    if (blockIdx.x == 0 && threadIdx.x == 0) rowstart[n] = total;
}

__global__ __launch_bounds__(256) void scatter_kernel(const int* __restrict__ src,
                                                      const int* __restrict__ dst,
                                                      const int* __restrict__ rowstart,
                                                      int* __restrict__ cursor,
                                                      int* __restrict__ bucket, int E) {
    int i = blockIdx.x * 256 + threadIdx.x;
    if (i < E) {
        int d = dst[i];
        int p = atomicAdd(&cursor[d], 1);
        bucket[rowstart[d] + p] = src[i];
    }
}

// ---------------- GEMM + attention coefficients ----------------
// feat (bf16) [N][128]; el/er f32 [N][8] computed from f32 accumulators.
__global__ __launch_bounds__(256) void gemm_attn(const float* __restrict__ in,
                                                 const float* __restrict__ W,
                                                 const float* __restrict__ al,
                                                 const float* __restrict__ ar,
                                                 __hip_bfloat16* __restrict__ feat,
                                                 float* __restrict__ el,
                                                 float* __restrict__ er, int N) {
    __shared__ float sIn[32][128];
    int tid = threadIdx.x;
    int c = tid & 127;
    int rgroup = tid >> 7;  // 0 or 1
    int blockrow = blockIdx.x * 32;

    for (int i = tid; i < 32 * 128; i += 256) {
        int r = i >> 7;
        int row = blockrow + r;
        sIn[r][i & 127] = (row < N) ? in[row * 128 + (i & 127)] : 0.0f;
    }
    __syncthreads();

    float acc[16];
#pragma unroll
    for (int r = 0; r < 16; ++r) acc[r] = 0.0f;
    int r0 = rgroup * 16;

    for (int k = 0; k < 128; k += 4) {
        float w0 = W[(k + 0) * 128 + c];
        float w1 = W[(k + 1) * 128 + c];
        float w2 = W[(k + 2) * 128 + c];
        float w3 = W[(k + 3) * 128 + c];
#pragma unroll
        for (int r = 0; r < 16; ++r) {
            float4 f = *reinterpret_cast<const float4*>(&sIn[r0 + r][k]);  // wave-uniform broadcast
            acc[r] += f.x * w0 + f.y * w1 + f.z * w2 + f.w * w3;
        }
    }

    int h = c >> 4;
    int d = c & 15;
    float alv = al[c];
    float arv = ar[c];
#pragma unroll
    for (int r = 0; r < 16; ++r) {
        int row = blockrow + r0 + r;
        if (row < N) {  // wave-uniform branch
            feat[row * 128 + c] = __float2bfloat16(acc[r]);
            float pl = acc[r] * alv;
            float pr = acc[r] * arv;
#pragma unroll
            for (int off = 8; off; off >>= 1) {
                pl += __shfl_xor(pl, off);
                pr += __shfl_xor(pr, off);
            }
            if (d == 0) {
                el[row * 8 + h] = pl;
                er[row * 8 + h] = pr;
            }
        }
    }
}

// ---------------- per-dst-node softmax + aggregation (atomic-free) ----------------
// one wave per node; lane owns components 2*lane, 2*lane+1; head h = lane>>3.
// Edge ids loaded coalesced (lane l loads bucket[beg+l]) and distributed via __shfl;
// edge loop processed in batches of 4 so 8 gathers are in flight per wait.
__global__ __launch_bounds__(256) void aggregate(const ushort* __restrict__ feat,  // bf16 bits
                                                 const float* __restrict__ el,
                                                 const float* __restrict__ er,
                                                 const int* __restrict__ rowstart,
                                                 const int* __restrict__ bucket,
                                                 const float* __restrict__ bias,
                                                 float* __restrict__ out,
                                                 int N, int do_relu) {
    int wid = (blockIdx.x * 256 + threadIdx.x) >> 6;
    int lane = threadIdx.x & 63;
    if (wid >= N) return;
    int h = lane >> 3;
    float er_h = er[wid * 8 + h];
    int beg = rowstart[wid];
    int end = rowstart[wid + 1];

    // lane's two feature components are the uint32 at index (s*64 + lane)
    const unsigned int* fp = reinterpret_cast<const unsigned int*>(feat) + lane;

    float l = 0.0f, ax = 0.0f, ay = 0.0f;

    for (int base = beg; base < end; base += 64) {
        int cnt = min(end - base, 64);
        int myedge = base + lane;
        int sv = (myedge < end) ? bucket[myedge] : 0;  // one coalesced load per 64 edges
        int k = 0;
        for (; k + 4 <= cnt; k += 4) {
            int s0 = __shfl(sv, k + 0);
            int s1 = __shfl(sv, k + 1);
            int s2 = __shfl(sv, k + 2);
            int s3 = __shfl(sv, k + 3);
            float e0 = el[s0 * 8 + h];
            float e1 = el[s1 * 8 + h];
            float e2 = el[s2 * 8 + h];
            float e3 = el[s3 * 8 + h];
            unsigned int u0 = fp[s0 * 64];
            unsigned int u1 = fp[s1 * 64];
            unsigned int u2 = fp[s2 * 64];
            unsigned int u3 = fp[s3 * 64];
            e0 += er_h; e1 += er_h; e2 += er_h; e3 += er_h;
            e0 = (e0 > 0.0f) ? e0 : LEAKY * e0;
            e1 = (e1 > 0.0f) ? e1 : LEAKY * e1;
            e2 = (e2 > 0.0f) ? e2 : LEAKY * e2;
            e3 = (e3 > 0.0f) ? e3 : LEAKY * e3;
            float p0 = __expf(e0), p1 = __expf(e1), p2 = __expf(e2), p3 = __expf(e3);
            l += (p0 + p1) + (p2 + p3);
            ax = fmaf(p0, __uint_as_float(u0 << 16), ax);
            ay = fmaf(p0, __uint_as_float(u0 & 0xffff0000u), ay);
            ax = fmaf(p1, __uint_as_float(u1 << 16), ax);
            ay = fmaf(p1, __uint_as_float(u1 & 0xffff0000u), ay);
            ax = fmaf(p2, __uint_as_float(u2 << 16), ax);
            ay = fmaf(p2, __uint_as_float(u2 & 0xffff0000u), ay);
            ax = fmaf(p3, __uint_as_float(u3 << 16), ax);
            ay = fmaf(p3, __uint_as_float(u3 & 0xffff0000u), ay);
        }
        for (; k < cnt; ++k) {
            int s = __shfl(sv, k);
            float e = el[s * 8 + h] + er_h;
            e = (e > 0.0f) ? e : LEAKY * e;
            float p = __expf(e);
            unsigned int u = fp[s * 64];
            l += p;
            ax = fmaf(p, __uint_as_float(u << 16), ax);
            ay = fmaf(p, __uint_as_float(u & 0xffff0000u), ay);
        }
    }

    float inv = (end > beg) ? 1.0f / l : 0.0f;
    int c = lane * 2;
    float2 bv = *reinterpret_cast<const float2*>(bias + c);
    float ox = fmaf(ax, inv, bv.x);
    float oy = fmaf(ay, inv, bv.y);
    if (do_relu) {
        ox = fmaxf(ox, 0.0f);
        oy = fmaxf(oy, 0.0f);
    }
    float2 o = {ox, oy};
    *reinterpret_cast<float2*>(out + wid * 128 + c) = o;
}

// ---------------- readout ----------------
// 256 blocks -> only 256 atomics per address (NOT per-node: 50000/address was the
// round-2 disaster, 2.4ms of same-address atomic serialization).
__global__ __launch_bounds__(256) void mean_reduce(const float* __restrict__ h,
                                                   float* __restrict__ meanbuf, int N) {
    int c = threadIdx.x & 127;
    int rbase = blockIdx.x * 2 + (threadIdx.x >> 7);
    float s = 0.0f;
    for (int r = rbase; r < N; r += gridDim.x * 2) s += h[r * 128 + c];
    atomicAdd(&meanbuf[c], s);
}

__global__ __launch_bounds__(64) void classifier(const float* __restrict__ meanbuf,
                                                 const float* __restrict__ Wc,
                                                 const float* __restrict__ bc,
                                                 float* __restrict__ outp, float invN) {
    int j = threadIdx.x;
    if (j < 10) {
        float s = 0.0f;
        for (int k = 0; k < 128; ++k) s += meanbuf[k] * invN * Wc[k * 10 + j];
        outp[j] = s + bc[j];
    }
}

// ---------------- launch ----------------

extern "C" void kernel_launch(void* const* d_in, const int* in_sizes, int n_in,
                              void* d_out, int out_size, void* d_ws, size_t ws_size,
                              hipStream_t stream) {
    const float* x   = (const float*)d_in[0];
    const int*   src = (const int*)d_in[1];
    const int*   dst = (const int*)d_in[2];
    const float* W1  = (const float*)d_in[3];
    const float* al1 = (const float*)d_in[4];
    const float* ar1 = (const float*)d_in[5];
    const float* b1  = (const float*)d_in[6];
    const float* W2  = (const float*)d_in[7];
    const float* al2 = (const float*)d_in[8];
    const float* ar2 = (const float*)d_in[9];
    const float* b2  = (const float*)d_in[10];
    const float* Wc  = (const float*)d_in[11];
    const float* bc  = (const float*)d_in[12];

    int N = in_sizes[0] / 128;
    int E = in_sizes[1];

    size_t off = 0;
    auto alloc = [&](size_t bytes) -> void* {
        void* p = (char*)d_ws + off;
        off += (bytes + 255) & ~size_t(255);
        return p;
    };
    int*   counts   = (int*)alloc(sizeof(int) * N);
    int*   rowstart = (int*)alloc(sizeof(int) * (N + 1));
    int*   cursor   = (int*)alloc(sizeof(int) * N);
    int*   tilesums = (int*)alloc(sizeof(int) * 256);
    int*   bucket   = (int*)alloc(sizeof(int) * E);
    __hip_bfloat16* feat = (__hip_bfloat16*)alloc(sizeof(__hip_bfloat16) * (size_t)N * 128);
    float* el       = (float*)alloc(sizeof(float) * N * 8);
    float* er       = (float*)alloc(sizeof(float) * N * 8);
    float* h1       = (float*)alloc(sizeof(float) * (size_t)N * 128);
    float* h2       = (float*)alloc(sizeof(float) * (size_t)N * 128);
    float* meanbuf  = (float*)alloc(sizeof(float) * 128);

    hipMemsetAsync(counts, 0, sizeof(int) * N, stream);
    hipMemsetAsync(cursor, 0, sizeof(int) * N, stream);
    hipMemsetAsync(meanbuf, 0, sizeof(float) * 128, stream);

    int numTiles = (N + 1023) / 1024;

    count_kernel<<<ceil_div(E, 256), 256, 0, stream>>>(dst, counts, E);
    scan_phase1<<<numTiles, 256, 0, stream>>>(counts, rowstart, tilesums, N);
    scan_phase2<<<1, 256, 0, stream>>>(tilesums, numTiles);
    scan_phase3<<<numTiles, 256, 0, stream>>>(rowstart, tilesums, N, E);
    scatter_kernel<<<ceil_div(E, 256), 256, 0, stream>>>(src, dst, rowstart, cursor, bucket, E);

    // layer 1
    gemm_attn<<<ceil_div(N, 32), 256, 0, stream>>>(x, W1, al1, ar1, feat, el, er, N);
    aggregate<<<ceil_div(N * 64, 256), 256, 0, stream>>>((const ushort*)feat, el, er, rowstart,
                                                         bucket, b1, h1, N, 1);
    // layer 2
    gemm_attn<<<ceil_div(N, 32), 256, 0, stream>>>(h1, W2, al2, ar2, feat, el, er, N);
    aggregate<<<ceil_div(N * 64, 256), 256, 0, stream>>>((const ushort*)feat, el, er, rowstart,
                                                         bucket, b2, h2, N, 0);
    // readout
    mean_reduce<<<256, 256, 0, stream>>>(h2, meanbuf, N);
    classifier<<<1, 64, 0, stream>>>(meanbuf, Wc, bc, (float*)d_out, 1.0f / (float)N);
}

// Round 4
// 273.313 us; speedup vs baseline: 9.8033x; 1.2233x over previous
//
#include <hip/hip_runtime.h>
#include <hip/hip_bf16.h>

#define LEAKY 0.2f

static inline int ceil_div(int a, int b) { return (a + b - 1) / b; }

typedef __bf16 bf16x8 __attribute__((ext_vector_type(8)));
typedef float f32x4 __attribute__((ext_vector_type(4)));

// f32 -> bf16 bits, round-to-nearest-even (values are finite; NaN path not needed)
__device__ __forceinline__ ushort f2bf(float f) {
    unsigned int x = __float_as_uint(f);
    unsigned int r = (x + 0x7fffu + ((x >> 16) & 1u)) >> 16;
    return (ushort)r;
}

// ---------------- CSR build ----------------

__global__ __launch_bounds__(256) void count_kernel(const int* __restrict__ dst,
                                                    int* __restrict__ counts, int E) {
    int i = blockIdx.x * 256 + threadIdx.x;
    if (i < E) atomicAdd(&counts[dst[i]], 1);
}

__global__ __launch_bounds__(256) void scan_phase1(const int* __restrict__ counts,
                                                   int* __restrict__ rowstart,
                                                   int* __restrict__ tilesums, int n) {
    __shared__ int sdata[256];
    int t = threadIdx.x;
    int base = blockIdx.x * 1024 + t * 4;
    int v[4];
    int s = 0;
#pragma unroll
    for (int j = 0; j < 4; ++j) {
        int idx = base + j;
        v[j] = (idx < n) ? counts[idx] : 0;
        s += v[j];
    }
    sdata[t] = s;
    __syncthreads();
    for (int off = 1; off < 256; off <<= 1) {
        int x = (t >= off) ? sdata[t - off] : 0;
        __syncthreads();
        sdata[t] += x;
        __syncthreads();
    }
    int excl = sdata[t] - s;
    if (t == 255) tilesums[blockIdx.x] = sdata[255];
    int run = excl;
#pragma unroll
    for (int j = 0; j < 4; ++j) {
        int idx = base + j;
        if (idx < n) rowstart[idx] = run;
        run += v[j];
    }
}

__global__ __launch_bounds__(256) void scan_phase2(int* __restrict__ tilesums, int nt) {
    __shared__ int sdata[256];
    int t = threadIdx.x;
    int v = (t < nt) ? tilesums[t] : 0;
    sdata[t] = v;
    __syncthreads();
    for (int off = 1; off < 256; off <<= 1) {
        int x = (t >= off) ? sdata[t - off] : 0;
        __syncthreads();
        sdata[t] += x;
        __syncthreads();
    }
    if (t < nt) tilesums[t] = sdata[t] - v;
}

__global__ __launch_bounds__(256) void scan_phase3(int* __restrict__ rowstart,
                                                   const int* __restrict__ tileoffs,
                                                   int n, int total) {
    int add = tileoffs[blockIdx.x];
    int base = blockIdx.x * 1024 + threadIdx.x * 4;
#pragma unroll
    for (int j = 0; j < 4; ++j) {
        int idx = base + j;
        if (idx < n) rowstart[idx] += add;
    }
    if (blockIdx.x == 0 && threadIdx.x == 0) rowstart[n] = total;
}

__global__ __launch_bounds__(256) void scatter_kernel(const int* __restrict__ src,
                                                      const int* __restrict__ dst,
                                                      const int* __restrict__ rowstart,
                                                      int* __restrict__ cursor,
                                                      int* __restrict__ bucket, int E) {
    int i = blockIdx.x * 256 + threadIdx.x;
    if (i < E) {
        int d = dst[i];
        int p = atomicAdd(&cursor[d], 1);
        bucket[rowstart[d] + p] = src[i];
    }
}

// ---------------- W convert: Wt[n][k] = bf16(W[k][n]) for both layers ----------------
__global__ __launch_bounds__(256) void convert_w(const float* __restrict__ W1,
                                                 const float* __restrict__ W2,
                                                 ushort* __restrict__ Wt1,
                                                 ushort* __restrict__ Wt2) {
    int idx = blockIdx.x * 256 + threadIdx.x;  // 0..32767
    const float* W = (idx < 16384) ? W1 : W2;
    ushort* O = (idx < 16384) ? Wt1 : Wt2;
    int i = idx & 16383;
    int k = i >> 7, n = i & 127;
    O[n * 128 + k] = f2bf(W[i]);
}

// ---------------- MFMA GEMM + attention coefficients ----------------
// feat[n][c] = sum_k in[n][k]*W[k][c]  via mfma_f32_16x16x32_bf16.
// Block: 64 rows x 128 cols, 4 waves as 2(M) x 2(N). Wave tile 32x64 = 2x4 frags.
// A: staged f32->bf16 in LDS, row padded to 136 bf16 (+16B) -> 2-way LDS conflicts (free).
// B: Wt[n][k] bf16 direct from global (32KB, L1/L2 resident).
// Fragment maps (guide §3, m89/m91-verified): A row=lane&15, k=(lane>>4)*8+j;
// B col=lane&15, k=(lane>>4)*8+j; C/D col=lane&15, row=(lane>>4)*4+reg.
#define LDK 136
__global__ __launch_bounds__(256) void gemm_attn_mfma(const float* __restrict__ in,
                                                      const ushort* __restrict__ Wt,
                                                      const float* __restrict__ al,
                                                      const float* __restrict__ ar,
                                                      ushort* __restrict__ feat,
                                                      float* __restrict__ el,
                                                      float* __restrict__ er, int N) {
    __shared__ ushort sA[64 * LDK];
    int tid = threadIdx.x;
    int rowbase = blockIdx.x * 64;

    // stage 64x128 f32 -> bf16 into padded LDS
#pragma unroll
    for (int i = 0; i < 8; ++i) {
        int idx4 = i * 256 + tid;     // float4 index
        int flat = idx4 * 4;
        int row = flat >> 7, col = flat & 127;
        int grow = rowbase + row;
        float4 v = make_float4(0.f, 0.f, 0.f, 0.f);
        if (grow < N) v = *reinterpret_cast<const float4*>(in + (size_t)grow * 128 + col);
        uint2 w;
        w.x = (unsigned int)f2bf(v.x) | ((unsigned int)f2bf(v.y) << 16);
        w.y = (unsigned int)f2bf(v.z) | ((unsigned int)f2bf(v.w) << 16);
        *reinterpret_cast<uint2*>(&sA[row * LDK + col]) = w;
    }
    __syncthreads();

    int wid = tid >> 6;
    int lane = tid & 63;
    int wm = wid >> 1;   // 0..1: row half
    int wn = wid & 1;    // 0..1: col half
    int l15 = lane & 15;
    int lhi = lane >> 4;

    f32x4 acc[2][4] = {};
    const ushort* wb = Wt + (size_t)(wn * 64 + l15) * 128 + lhi * 8;
    const ushort* a0p = &sA[(wm * 32 + l15) * LDK + lhi * 8];
    const ushort* a1p = &sA[(wm * 32 + 16 + l15) * LDK + lhi * 8];

#pragma unroll
    for (int ks = 0; ks < 4; ++ks) {
        bf16x8 a0 = *reinterpret_cast<const bf16x8*>(a0p + ks * 32);
        bf16x8 a1 = *reinterpret_cast<const bf16x8*>(a1p + ks * 32);
#pragma unroll
        for (int ni = 0; ni < 4; ++ni) {
            bf16x8 b = *reinterpret_cast<const bf16x8*>(wb + ni * 16 * 128 + ks * 32);
            acc[0][ni] = __builtin_amdgcn_mfma_f32_16x16x32_bf16(a0, b, acc[0][ni], 0, 0, 0);
            acc[1][ni] = __builtin_amdgcn_mfma_f32_16x16x32_bf16(a1, b, acc[1][ni], 0, 0, 0);
        }
    }

    // epilogue: feat (bf16) + el/er head reductions
#pragma unroll
    for (int ni = 0; ni < 4; ++ni) {
        int head = wn * 4 + ni;
        float alv = al[head * 16 + l15];
        float arv = ar[head * 16 + l15];
#pragma unroll
        for (int mi = 0; mi < 2; ++mi) {
#pragma unroll
            for (int reg = 0; reg < 4; ++reg) {
                int row = rowbase + wm * 32 + mi * 16 + lhi * 4 + reg;
                float v = acc[mi][ni][reg];
                float pl = v * alv;
                float pr = v * arv;
#pragma unroll
                for (int off = 8; off; off >>= 1) {
                    pl += __shfl_xor(pl, off);
                    pr += __shfl_xor(pr, off);
                }
                if (row < N) {
                    feat[(size_t)row * 128 + head * 16 + l15] = f2bf(v);
                    if (l15 == 0) {
                        el[row * 8 + head] = pl;
                        er[row * 8 + head] = pr;
                    }
                }
            }
        }
    }
}

// ---------------- per-dst-node softmax + aggregation (atomic-free) ----------------
// one wave per node; lane owns components 2*lane, 2*lane+1; head h = lane>>3.
// Edge ids loaded coalesced and distributed via __shfl; batch of 8 edges in flight.
__global__ __launch_bounds__(256) void aggregate(const ushort* __restrict__ feat,  // bf16 bits
                                                 const float* __restrict__ el,
                                                 const float* __restrict__ er,
                                                 const int* __restrict__ rowstart,
                                                 const int* __restrict__ bucket,
                                                 const float* __restrict__ bias,
                                                 float* __restrict__ out,
                                                 int N, int do_relu) {
    int wid = (blockIdx.x * 256 + threadIdx.x) >> 6;
    int lane = threadIdx.x & 63;
    if (wid >= N) return;
    int h = lane >> 3;
    float er_h = er[wid * 8 + h];
    int beg = rowstart[wid];
    int end = rowstart[wid + 1];

    const unsigned int* fp = reinterpret_cast<const unsigned int*>(feat) + lane;

    float l = 0.0f, ax = 0.0f, ay = 0.0f;

    for (int base = beg; base < end; base += 64) {
        int cnt = min(end - base, 64);
        int myedge = base + lane;
        int sv = (myedge < end) ? bucket[myedge] : 0;  // one coalesced load per 64 edges
        int k = 0;
        for (; k + 8 <= cnt; k += 8) {
            int ss[8];
            float ee[8];
            unsigned int uu[8];
#pragma unroll
            for (int q = 0; q < 8; ++q) ss[q] = __shfl(sv, k + q);
#pragma unroll
            for (int q = 0; q < 8; ++q) ee[q] = el[ss[q] * 8 + h];
#pragma unroll
            for (int q = 0; q < 8; ++q) uu[q] = fp[ss[q] * 64];
#pragma unroll
            for (int q = 0; q < 8; ++q) {
                float e = ee[q] + er_h;
                e = (e > 0.0f) ? e : LEAKY * e;
                float p = __expf(e);
                l += p;
                ax = fmaf(p, __uint_as_float(uu[q] << 16), ax);
                ay = fmaf(p, __uint_as_float(uu[q] & 0xffff0000u), ay);
            }
        }
        for (; k < cnt; ++k) {
            int s = __shfl(sv, k);
            float e = el[s * 8 + h] + er_h;
            e = (e > 0.0f) ? e : LEAKY * e;
            float p = __expf(e);
            unsigned int u = fp[s * 64];
            l += p;
            ax = fmaf(p, __uint_as_float(u << 16), ax);
            ay = fmaf(p, __uint_as_float(u & 0xffff0000u), ay);
        }
    }

    float inv = (end > beg) ? 1.0f / l : 0.0f;
    int c = lane * 2;
    float2 bv = *reinterpret_cast<const float2*>(bias + c);
    float ox = fmaf(ax, inv, bv.x);
    float oy = fmaf(ay, inv, bv.y);
    if (do_relu) {
        ox = fmaxf(ox, 0.0f);
        oy = fmaxf(oy, 0.0f);
    }
    float2 o = {ox, oy};
    *reinterpret_cast<float2*>(out + (size_t)wid * 128 + c) = o;
}

// ---------------- readout ----------------
// 256 blocks -> only 256 atomics per address (per-node atomics were the round-2 disaster).
__global__ __launch_bounds__(256) void mean_reduce(const float* __restrict__ h,
                                                   float* __restrict__ meanbuf, int N) {
    int c = threadIdx.x & 127;
    int rbase = blockIdx.x * 2 + (threadIdx.x >> 7);
    float s = 0.0f;
    for (int r = rbase; r < N; r += gridDim.x * 2) s += h[r * 128 + c];
    atomicAdd(&meanbuf[c], s);
}

__global__ __launch_bounds__(64) void classifier(const float* __restrict__ meanbuf,
                                                 const float* __restrict__ Wc,
                                                 const float* __restrict__ bc,
                                                 float* __restrict__ outp, float invN) {
    int j = threadIdx.x;
    if (j < 10) {
        float s = 0.0f;
        for (int k = 0; k < 128; ++k) s += meanbuf[k] * invN * Wc[k * 10 + j];
        outp[j] = s + bc[j];
    }
}

// ---------------- launch ----------------

extern "C" void kernel_launch(void* const* d_in, const int* in_sizes, int n_in,
                              void* d_out, int out_size, void* d_ws, size_t ws_size,
                              hipStream_t stream) {
    const float* x   = (const float*)d_in[0];
    const int*   src = (const int*)d_in[1];
    const int*   dst = (const int*)d_in[2];
    const float* W1  = (const float*)d_in[3];
    const float* al1 = (const float*)d_in[4];
    const float* ar1 = (const float*)d_in[5];
    const float* b1  = (const float*)d_in[6];
    const float* W2  = (const float*)d_in[7];
    const float* al2 = (const float*)d_in[8];
    const float* ar2 = (const float*)d_in[9];
    const float* b2  = (const float*)d_in[10];
    const float* Wc  = (const float*)d_in[11];
    const float* bc  = (const float*)d_in[12];

    int N = in_sizes[0] / 128;
    int E = in_sizes[1];

    size_t off = 0;
    auto alloc = [&](size_t bytes) -> void* {
        void* p = (char*)d_ws + off;
        off += (bytes + 255) & ~size_t(255);
        return p;
    };
    int*   counts   = (int*)alloc(sizeof(int) * N);
    int*   rowstart = (int*)alloc(sizeof(int) * (N + 1));
    int*   cursor   = (int*)alloc(sizeof(int) * N);
    int*   tilesums = (int*)alloc(sizeof(int) * 256);
    int*   bucket   = (int*)alloc(sizeof(int) * E);
    ushort* feat    = (ushort*)alloc(sizeof(ushort) * (size_t)N * 128);
    float* el       = (float*)alloc(sizeof(float) * N * 8);
    float* er       = (float*)alloc(sizeof(float) * N * 8);
    float* h1       = (float*)alloc(sizeof(float) * (size_t)N * 128);
    float* h2       = (float*)alloc(sizeof(float) * (size_t)N * 128);
    float* meanbuf  = (float*)alloc(sizeof(float) * 128);
    ushort* Wt1     = (ushort*)alloc(sizeof(ushort) * 128 * 128);
    ushort* Wt2     = (ushort*)alloc(sizeof(ushort) * 128 * 128);

    hipMemsetAsync(counts, 0, sizeof(int) * N, stream);
    hipMemsetAsync(cursor, 0, sizeof(int) * N, stream);
    hipMemsetAsync(meanbuf, 0, sizeof(float) * 128, stream);

    int numTiles = (N + 1023) / 1024;

    count_kernel<<<ceil_div(E, 256), 256, 0, stream>>>(dst, counts, E);
    scan_phase1<<<numTiles, 256, 0, stream>>>(counts, rowstart, tilesums, N);
    scan_phase2<<<1, 256, 0, stream>>>(tilesums, numTiles);
    scan_phase3<<<numTiles, 256, 0, stream>>>(rowstart, tilesums, N, E);
    scatter_kernel<<<ceil_div(E, 256), 256, 0, stream>>>(src, dst, rowstart, cursor, bucket, E);
    convert_w<<<128, 256, 0, stream>>>(W1, W2, Wt1, Wt2);

    // layer 1
    gemm_attn_mfma<<<ceil_div(N, 64), 256, 0, stream>>>(x, Wt1, al1, ar1, feat, el, er, N);
    aggregate<<<ceil_div(N * 64, 256), 256, 0, stream>>>(feat, el, er, rowstart, bucket, b1, h1, N, 1);
    // layer 2
    gemm_attn_mfma<<<ceil_div(N, 64), 256, 0, stream>>>(h1, Wt2, al2, ar2, feat, el, er, N);
    aggregate<<<ceil_div(N * 64, 256), 256, 0, stream>>>(feat, el, er, rowstart, bucket, b2, h2, N, 0);
    // readout
    mean_reduce<<<256, 256, 0, stream>>>(h2, meanbuf, N);
    classifier<<<1, 64, 0, stream>>>(meanbuf, Wc, bc, (float*)d_out, 1.0f / (float)N);
}

// Round 5
// 216.693 us; speedup vs baseline: 12.3647x; 1.2613x over previous
//
#include <hip/hip_runtime.h>
#include <hip/hip_bf16.h>

#define LEAKY 0.2f
#define BINB 8          // 256 nodes per bin (requires N <= 65536 for u16 packing)
#define TILE 4096       // edges per block in binning kernels
#define CAP 8192        // LDS bucket-segment capacity per bin (avg ~4081, 45+ sigma headroom)

static inline int ceil_div(int a, int b) { return (a + b - 1) / b; }

typedef __bf16 bf16x8 __attribute__((ext_vector_type(8)));
typedef float f32x4 __attribute__((ext_vector_type(4)));

// f32 -> bf16 bits, round-to-nearest-even
__device__ __forceinline__ ushort f2bf(float f) {
    unsigned int x = __float_as_uint(f);
    unsigned int r = (x + 0x7fffu + ((x >> 16) & 1u)) >> 16;
    return (ushort)r;
}

// ---------------- CSR build (two-level, coalesced writes) ----------------
// Round-4 lesson: one-pass random 4B scatter = 17x HBM write amplification
// (800k x 64B granule = 55MB for a 3.2MB array). Build instead via coarse bins
// with LDS reorder so all global writes are (near-)contiguous.

__global__ __launch_bounds__(256) void bin_count(const int* __restrict__ dst,
                                                 int* __restrict__ bin_cnt, int E, int NB) {
    __shared__ int h[256];
    int t = threadIdx.x;
    h[t] = 0;
    __syncthreads();
    int base = blockIdx.x * TILE;
#pragma unroll
    for (int j = 0; j < TILE / 256; ++j) {
        int i = base + j * 256 + t;
        if (i < E) atomicAdd(&h[dst[i] >> BINB], 1);
    }
    __syncthreads();
    if (t < NB && h[t]) atomicAdd(&bin_cnt[t], h[t]);
}

__global__ __launch_bounds__(256) void bin_scan(const int* __restrict__ bin_cnt,
                                                int* __restrict__ binStart,
                                                int* __restrict__ bin_cursor,
                                                int* __restrict__ rowstart,
                                                int NB, int N, int E) {
    __shared__ int s[256];
    int t = threadIdx.x;
    int v = (t < NB) ? bin_cnt[t] : 0;
    s[t] = v;
    __syncthreads();
    for (int off = 1; off < 256; off <<= 1) {
        int x = (t >= off) ? s[t - off] : 0;
        __syncthreads();
        s[t] += x;
        __syncthreads();
    }
    int excl = s[t] - v;
    if (t < NB) {
        binStart[t] = excl;
        bin_cursor[t] = excl;
        if (t == NB - 1) binStart[NB] = excl + v;
    }
    if (t == 0) rowstart[N] = E;
}

// Per-block: LDS histogram + scan + reorder, then contiguous-run global writes.
__global__ __launch_bounds__(256) void bin_scatter(const int* __restrict__ src,
                                                   const int* __restrict__ dst,
                                                   int* __restrict__ bin_cursor,
                                                   unsigned int* __restrict__ coarse, int E) {
    __shared__ int hist[256], scn[256], gbase[256], lcur[256];
    __shared__ unsigned int outp[TILE];
    __shared__ int gidx[TILE];
    int t = threadIdx.x;
    hist[t] = 0;
    __syncthreads();
    int base = blockIdx.x * TILE;
    int dloc[TILE / 256];
#pragma unroll
    for (int j = 0; j < TILE / 256; ++j) {
        int i = base + j * 256 + t;
        int d = (i < E) ? dst[i] : -1;
        dloc[j] = d;
        if (d >= 0) atomicAdd(&hist[d >> BINB], 1);
    }
    __syncthreads();
    int hv = hist[t];
    scn[t] = hv;
    __syncthreads();
    for (int off = 1; off < 256; off <<= 1) {
        int x = (t >= off) ? scn[t - off] : 0;
        __syncthreads();
        scn[t] += x;
        __syncthreads();
    }
    int excl = scn[t] - hv;                         // exclusive within block
    if (hv > 0) gbase[t] = atomicAdd(&bin_cursor[t], hv);  // reserve global run
    lcur[t] = excl;
    scn[t] = excl;  // own slot overwrite; next read is after the barrier below
    __syncthreads();
#pragma unroll
    for (int j = 0; j < TILE / 256; ++j) {
        int i = base + j * 256 + t;
        int d = dloc[j];
        if (d >= 0) {
            int b = d >> BINB;
            int pos = atomicAdd(&lcur[b], 1);
            outp[pos] = (unsigned int)src[i] | ((unsigned int)(d & ((1 << BINB) - 1)) << 16);
            gidx[pos] = gbase[b] + (pos - scn[b]);
        }
    }
    __syncthreads();
    int cnt = min(TILE, E - base);
    for (int j = t; j < cnt; j += 256) coarse[gidx[j]] = outp[j];  // contiguous runs per bin
}

// One block per bin: build this bin's rowstart + bucket segment entirely in LDS,
// flush coalesced. bucket entries are u16 (src < 65536).
__global__ __launch_bounds__(256) void fine_csr(const unsigned int* __restrict__ coarse,
                                                const int* __restrict__ binStart,
                                                int* __restrict__ rowstart,
                                                ushort* __restrict__ bucket, int N) {
    __shared__ int hist[256], scn[256], cur[256];
    __shared__ ushort sb[CAP];
    int b = blockIdx.x, t = threadIdx.x;
    int e0 = binStart[b], e1 = binStart[b + 1];
    int cnt = e1 - e0;
    hist[t] = 0;
    __syncthreads();
    for (int j = e0 + t; j < e1; j += 256) atomicAdd(&hist[coarse[j] >> 16], 1);
    __syncthreads();
    int hv = hist[t];
    scn[t] = hv;
    __syncthreads();
    for (int off = 1; off < 256; off <<= 1) {
        int x = (t >= off) ? scn[t - off] : 0;
        __syncthreads();
        scn[t] += x;
        __syncthreads();
    }
    int excl = scn[t] - hv;
    int n = (b << BINB) + t;
    if (n < N) rowstart[n] = e0 + excl;
    cur[t] = excl;
    __syncthreads();
    bool fit = (cnt <= CAP);
    for (int j = e0 + t; j < e1; j += 256) {
        unsigned int p = coarse[j];
        int dl = p >> 16;
        int pos = atomicAdd(&cur[dl], 1);
        ushort sv = (ushort)(p & 0xffffu);
        if (fit) sb[pos] = sv;
        else bucket[e0 + pos] = sv;  // statistical never; correctness fallback
    }
    __syncthreads();
    if (fit)
        for (int j = t; j < cnt; j += 256) bucket[e0 + j] = sb[j];
}

// ---------------- W convert: Wt[n][k] = bf16(W[k][n]) for both layers ----------------
__global__ __launch_bounds__(256) void convert_w(const float* __restrict__ W1,
                                                 const float* __restrict__ W2,
                                                 ushort* __restrict__ Wt1,
                                                 ushort* __restrict__ Wt2) {
    int idx = blockIdx.x * 256 + threadIdx.x;  // 0..32767
    const float* W = (idx < 16384) ? W1 : W2;
    ushort* O = (idx < 16384) ? Wt1 : Wt2;
    int i = idx & 16383;
    int k = i >> 7, n = i & 127;
    O[n * 128 + k] = f2bf(W[i]);
}

// ---------------- MFMA GEMM + attention coefficients ----------------
// Block: 64 rows x 128 cols, 4 waves as 2(M) x 2(N). Wave tile 32x64 = 2x4 frags.
// A: staged f32->bf16 in LDS (+16B row pad -> only 2-way conflicts, free).
// B: Wt[n][k] bf16 direct from global (32KB, L1/L2 resident).
#define LDK 136
__global__ __launch_bounds__(256) void gemm_attn_mfma(const float* __restrict__ in,
                                                      const ushort* __restrict__ Wt,
                                                      const float* __restrict__ al,
                                                      const float* __restrict__ ar,
                                                      ushort* __restrict__ feat,
                                                      float* __restrict__ el,
                                                      float* __restrict__ er, int N) {
    __shared__ ushort sA[64 * LDK];
    int tid = threadIdx.x;
    int rowbase = blockIdx.x * 64;

#pragma unroll
    for (int i = 0; i < 8; ++i) {
        int idx4 = i * 256 + tid;
        int flat = idx4 * 4;
        int row = flat >> 7, col = flat & 127;
        int grow = rowbase + row;
        float4 v = make_float4(0.f, 0.f, 0.f, 0.f);
        if (grow < N) v = *reinterpret_cast<const float4*>(in + (size_t)grow * 128 + col);
        uint2 w;
        w.x = (unsigned int)f2bf(v.x) | ((unsigned int)f2bf(v.y) << 16);
        w.y = (unsigned int)f2bf(v.z) | ((unsigned int)f2bf(v.w) << 16);
        *reinterpret_cast<uint2*>(&sA[row * LDK + col]) = w;
    }
    __syncthreads();

    int wid = tid >> 6;
    int lane = tid & 63;
    int wm = wid >> 1;
    int wn = wid & 1;
    int l15 = lane & 15;
    int lhi = lane >> 4;

    f32x4 acc[2][4] = {};
    const ushort* wb = Wt + (size_t)(wn * 64 + l15) * 128 + lhi * 8;
    const ushort* a0p = &sA[(wm * 32 + l15) * LDK + lhi * 8];
    const ushort* a1p = &sA[(wm * 32 + 16 + l15) * LDK + lhi * 8];

#pragma unroll
    for (int ks = 0; ks < 4; ++ks) {
        bf16x8 a0 = *reinterpret_cast<const bf16x8*>(a0p + ks * 32);
        bf16x8 a1 = *reinterpret_cast<const bf16x8*>(a1p + ks * 32);
#pragma unroll
        for (int ni = 0; ni < 4; ++ni) {
            bf16x8 b = *reinterpret_cast<const bf16x8*>(wb + ni * 16 * 128 + ks * 32);
            acc[0][ni] = __builtin_amdgcn_mfma_f32_16x16x32_bf16(a0, b, acc[0][ni], 0, 0, 0);
            acc[1][ni] = __builtin_amdgcn_mfma_f32_16x16x32_bf16(a1, b, acc[1][ni], 0, 0, 0);
        }
    }

#pragma unroll
    for (int ni = 0; ni < 4; ++ni) {
        int head = wn * 4 + ni;
        float alv = al[head * 16 + l15];
        float arv = ar[head * 16 + l15];
#pragma unroll
        for (int mi = 0; mi < 2; ++mi) {
#pragma unroll
            for (int reg = 0; reg < 4; ++reg) {
                int row = rowbase + wm * 32 + mi * 16 + lhi * 4 + reg;
                float v = acc[mi][ni][reg];
                float pl = v * alv;
                float pr = v * arv;
#pragma unroll
                for (int off = 8; off; off >>= 1) {
                    pl += __shfl_xor(pl, off);
                    pr += __shfl_xor(pr, off);
                }
                if (row < N) {
                    feat[(size_t)row * 128 + head * 16 + l15] = f2bf(v);
                    if (l15 == 0) {
                        el[row * 8 + head] = pl;
                        er[row * 8 + head] = pr;
                    }
                }
            }
        }
    }
}

// ---------------- per-dst-node softmax + aggregation (atomic-free) ----------------
__global__ __launch_bounds__(256) void aggregate(const ushort* __restrict__ feat,  // bf16 bits
                                                 const float* __restrict__ el,
                                                 const float* __restrict__ er,
                                                 const int* __restrict__ rowstart,
                                                 const ushort* __restrict__ bucket,
                                                 const float* __restrict__ bias,
                                                 float* __restrict__ out,
                                                 int N, int do_relu) {
    int wid = (blockIdx.x * 256 + threadIdx.x) >> 6;
    int lane = threadIdx.x & 63;
    if (wid >= N) return;
    int h = lane >> 3;
    float er_h = er[wid * 8 + h];
    int beg = rowstart[wid];
    int end = rowstart[wid + 1];

    const unsigned int* fp = reinterpret_cast<const unsigned int*>(feat) + lane;

    float l = 0.0f, ax = 0.0f, ay = 0.0f;

    for (int base = beg; base < end; base += 64) {
        int cnt = min(end - base, 64);
        int myedge = base + lane;
        int sv = (myedge < end) ? (int)bucket[myedge] : 0;  // coalesced u16 load, 64 edges
        int k = 0;
        for (; k + 8 <= cnt; k += 8) {
            int ss[8];
            float ee[8];
            unsigned int uu[8];
#pragma unroll
            for (int q = 0; q < 8; ++q) ss[q] = __shfl(sv, k + q);
#pragma unroll
            for (int q = 0; q < 8; ++q) ee[q] = el[ss[q] * 8 + h];
#pragma unroll
            for (int q = 0; q < 8; ++q) uu[q] = fp[ss[q] * 64];
#pragma unroll
            for (int q = 0; q < 8; ++q) {
                float e = ee[q] + er_h;
                e = (e > 0.0f) ? e : LEAKY * e;
                float p = __expf(e);
                l += p;
                ax = fmaf(p, __uint_as_float(uu[q] << 16), ax);
                ay = fmaf(p, __uint_as_float(uu[q] & 0xffff0000u), ay);
            }
        }
        for (; k < cnt; ++k) {
            int s = __shfl(sv, k);
            float e = el[s * 8 + h] + er_h;
            e = (e > 0.0f) ? e : LEAKY * e;
            float p = __expf(e);
            unsigned int u = fp[s * 64];
            l += p;
            ax = fmaf(p, __uint_as_float(u << 16), ax);
            ay = fmaf(p, __uint_as_float(u & 0xffff0000u), ay);
        }
    }

    float inv = (end > beg) ? 1.0f / l : 0.0f;
    int c = lane * 2;
    float2 bv = *reinterpret_cast<const float2*>(bias + c);
    float ox = fmaf(ax, inv, bv.x);
    float oy = fmaf(ay, inv, bv.y);
    if (do_relu) {
        ox = fmaxf(ox, 0.0f);
        oy = fmaxf(oy, 0.0f);
    }
    float2 o = {ox, oy};
    *reinterpret_cast<float2*>(out + (size_t)wid * 128 + c) = o;
}

// ---------------- readout ----------------
__global__ __launch_bounds__(256) void mean_reduce(const float* __restrict__ h,
                                                   float* __restrict__ meanbuf, int N) {
    int c = threadIdx.x & 127;
    int rbase = blockIdx.x * 2 + (threadIdx.x >> 7);
    float s = 0.0f;
    for (int r = rbase; r < N; r += gridDim.x * 2) s += h[r * 128 + c];
    atomicAdd(&meanbuf[c], s);
}

__global__ __launch_bounds__(64) void classifier(const float* __restrict__ meanbuf,
                                                 const float* __restrict__ Wc,
                                                 const float* __restrict__ bc,
                                                 float* __restrict__ outp, float invN) {
    int j = threadIdx.x;
    if (j < 10) {
        float s = 0.0f;
        for (int k = 0; k < 128; ++k) s += meanbuf[k] * invN * Wc[k * 10 + j];
        outp[j] = s + bc[j];
    }
}

// ---------------- launch ----------------

extern "C" void kernel_launch(void* const* d_in, const int* in_sizes, int n_in,
                              void* d_out, int out_size, void* d_ws, size_t ws_size,
                              hipStream_t stream) {
    const float* x   = (const float*)d_in[0];
    const int*   src = (const int*)d_in[1];
    const int*   dst = (const int*)d_in[2];
    const float* W1  = (const float*)d_in[3];
    const float* al1 = (const float*)d_in[4];
    const float* ar1 = (const float*)d_in[5];
    const float* b1  = (const float*)d_in[6];
    const float* W2  = (const float*)d_in[7];
    const float* al2 = (const float*)d_in[8];
    const float* ar2 = (const float*)d_in[9];
    const float* b2  = (const float*)d_in[10];
    const float* Wc  = (const float*)d_in[11];
    const float* bc  = (const float*)d_in[12];

    int N = in_sizes[0] / 128;
    int E = in_sizes[1];
    int NB = (N + (1 << BINB) - 1) >> BINB;  // 196 bins

    size_t off = 0;
    auto alloc = [&](size_t bytes) -> void* {
        void* p = (char*)d_ws + off;
        off += (bytes + 255) & ~size_t(255);
        return p;
    };
    int*   bin_cnt    = (int*)alloc(sizeof(int) * NB);
    int*   binStart   = (int*)alloc(sizeof(int) * (NB + 1));
    int*   bin_cursor = (int*)alloc(sizeof(int) * NB);
    int*   rowstart   = (int*)alloc(sizeof(int) * (N + 1));
    unsigned int* coarse = (unsigned int*)alloc(sizeof(unsigned int) * E);
    ushort* bucket  = (ushort*)alloc(sizeof(ushort) * E);
    ushort* feat    = (ushort*)alloc(sizeof(ushort) * (size_t)N * 128);
    float* el       = (float*)alloc(sizeof(float) * N * 8);
    float* er       = (float*)alloc(sizeof(float) * N * 8);
    float* h1       = (float*)alloc(sizeof(float) * (size_t)N * 128);
    float* h2       = (float*)alloc(sizeof(float) * (size_t)N * 128);
    float* meanbuf  = (float*)alloc(sizeof(float) * 128);
    ushort* Wt1     = (ushort*)alloc(sizeof(ushort) * 128 * 128);
    ushort* Wt2     = (ushort*)alloc(sizeof(ushort) * 128 * 128);

    hipMemsetAsync(bin_cnt, 0, sizeof(int) * NB, stream);
    hipMemsetAsync(meanbuf, 0, sizeof(float) * 128, stream);

    int GB = ceil_div(E, TILE);  // 196

    bin_count<<<GB, 256, 0, stream>>>(dst, bin_cnt, E, NB);
    bin_scan<<<1, 256, 0, stream>>>(bin_cnt, binStart, bin_cursor, rowstart, NB, N, E);
    bin_scatter<<<GB, 256, 0, stream>>>(src, dst, bin_cursor, coarse, E);
    fine_csr<<<NB, 256, 0, stream>>>(coarse, binStart, rowstart, bucket, N);
    convert_w<<<128, 256, 0, stream>>>(W1, W2, Wt1, Wt2);

    // layer 1
    gemm_attn_mfma<<<ceil_div(N, 64), 256, 0, stream>>>(x, Wt1, al1, ar1, feat, el, er, N);
    aggregate<<<ceil_div(N * 64, 256), 256, 0, stream>>>(feat, el, er, rowstart, bucket, b1, h1, N, 1);
    // layer 2
    gemm_attn_mfma<<<ceil_div(N, 64), 256, 0, stream>>>(h1, Wt2, al2, ar2, feat, el, er, N);
    aggregate<<<ceil_div(N * 64, 256), 256, 0, stream>>>(feat, el, er, rowstart, bucket, b2, h2, N, 0);
    // readout
    mean_reduce<<<256, 256, 0, stream>>>(h2, meanbuf, N);
    classifier<<<1, 64, 0, stream>>>(meanbuf, Wc, bc, (float*)d_out, 1.0f / (float)N);
}

// Round 6
// 214.398 us; speedup vs baseline: 12.4971x; 1.0107x over previous
//
#include <hip/hip_runtime.h>
#include <hip/hip_bf16.h>

#define LEAKY 0.2f
#define BINB 8          // 256 nodes per bin (requires N <= 65536 for u16 packing)
#define TILE 4096       // edges per block in binning kernels
#define CAP 8192        // LDS bucket-segment capacity per bin (avg ~4081)

static inline int ceil_div(int a, int b) { return (a + b - 1) / b; }

typedef __bf16 bf16x8 __attribute__((ext_vector_type(8)));
typedef float f32x4 __attribute__((ext_vector_type(4)));

// f32 -> bf16 bits, round-to-nearest-even
__device__ __forceinline__ ushort f2bf(float f) {
    unsigned int x = __float_as_uint(f);
    unsigned int r = (x + 0x7fffu + ((x >> 16) & 1u)) >> 16;
    return (ushort)r;
}

// ---------------- CSR build (two-level, coalesced writes) ----------------
// Round-4 lesson: one-pass random 4B scatter = 17x HBM write amplification.

__global__ __launch_bounds__(256) void bin_count(const int* __restrict__ dst,
                                                 int* __restrict__ bin_cnt, int E, int NB) {
    __shared__ int h[256];
    int t = threadIdx.x;
    h[t] = 0;
    __syncthreads();
    int base = blockIdx.x * TILE;
#pragma unroll
    for (int j = 0; j < TILE / 256; ++j) {
        int i = base + j * 256 + t;
        if (i < E) atomicAdd(&h[dst[i] >> BINB], 1);
    }
    __syncthreads();
    if (t < NB && h[t]) atomicAdd(&bin_cnt[t], h[t]);
}

__global__ __launch_bounds__(256) void bin_scan(const int* __restrict__ bin_cnt,
                                                int* __restrict__ binStart,
                                                int* __restrict__ bin_cursor,
                                                int* __restrict__ rowstart,
                                                int NB, int N, int E) {
    __shared__ int s[256];
    int t = threadIdx.x;
    int v = (t < NB) ? bin_cnt[t] : 0;
    s[t] = v;
    __syncthreads();
    for (int off = 1; off < 256; off <<= 1) {
        int x = (t >= off) ? s[t - off] : 0;
        __syncthreads();
        s[t] += x;
        __syncthreads();
    }
    int excl = s[t] - v;
    if (t < NB) {
        binStart[t] = excl;
        bin_cursor[t] = excl;
        if (t == NB - 1) binStart[NB] = excl + v;
    }
    if (t == 0) rowstart[N] = E;
}

__global__ __launch_bounds__(256) void bin_scatter(const int* __restrict__ src,
                                                   const int* __restrict__ dst,
                                                   int* __restrict__ bin_cursor,
                                                   unsigned int* __restrict__ coarse, int E) {
    __shared__ int hist[256], scn[256], gbase[256], lcur[256];
    __shared__ unsigned int outp[TILE];
    __shared__ int gidx[TILE];
    int t = threadIdx.x;
    hist[t] = 0;
    __syncthreads();
    int base = blockIdx.x * TILE;
    int dloc[TILE / 256];
#pragma unroll
    for (int j = 0; j < TILE / 256; ++j) {
        int i = base + j * 256 + t;
        int d = (i < E) ? dst[i] : -1;
        dloc[j] = d;
        if (d >= 0) atomicAdd(&hist[d >> BINB], 1);
    }
    __syncthreads();
    int hv = hist[t];
    scn[t] = hv;
    __syncthreads();
    for (int off = 1; off < 256; off <<= 1) {
        int x = (t >= off) ? scn[t - off] : 0;
        __syncthreads();
        scn[t] += x;
        __syncthreads();
    }
    int excl = scn[t] - hv;
    if (hv > 0) gbase[t] = atomicAdd(&bin_cursor[t], hv);
    lcur[t] = excl;
    scn[t] = excl;
    __syncthreads();
#pragma unroll
    for (int j = 0; j < TILE / 256; ++j) {
        int i = base + j * 256 + t;
        int d = dloc[j];
        if (d >= 0) {
            int b = d >> BINB;
            int pos = atomicAdd(&lcur[b], 1);
            outp[pos] = (unsigned int)src[i] | ((unsigned int)(d & ((1 << BINB) - 1)) << 16);
            gidx[pos] = gbase[b] + (pos - scn[b]);
        }
    }
    __syncthreads();
    int cnt = min(TILE, E - base);
    for (int j = t; j < cnt; j += 256) coarse[gidx[j]] = outp[j];
}

__global__ __launch_bounds__(256) void fine_csr(const unsigned int* __restrict__ coarse,
                                                const int* __restrict__ binStart,
                                                int* __restrict__ rowstart,
                                                ushort* __restrict__ bucket, int N) {
    __shared__ int hist[256], scn[256], cur[256];
    __shared__ ushort sb[CAP];
    int b = blockIdx.x, t = threadIdx.x;
    int e0 = binStart[b], e1 = binStart[b + 1];
    int cnt = e1 - e0;
    hist[t] = 0;
    __syncthreads();
    for (int j = e0 + t; j < e1; j += 256) atomicAdd(&hist[coarse[j] >> 16], 1);
    __syncthreads();
    int hv = hist[t];
    scn[t] = hv;
    __syncthreads();
    for (int off = 1; off < 256; off <<= 1) {
        int x = (t >= off) ? scn[t - off] : 0;
        __syncthreads();
        scn[t] += x;
        __syncthreads();
    }
    int excl = scn[t] - hv;
    int n = (b << BINB) + t;
    if (n < N) rowstart[n] = e0 + excl;
    cur[t] = excl;
    __syncthreads();
    bool fit = (cnt <= CAP);
    for (int j = e0 + t; j < e1; j += 256) {
        unsigned int p = coarse[j];
        int dl = p >> 16;
        int pos = atomicAdd(&cur[dl], 1);
        ushort sv = (ushort)(p & 0xffffu);
        if (fit) sb[pos] = sv;
        else bucket[e0 + pos] = sv;
    }
    __syncthreads();
    if (fit)
        for (int j = t; j < cnt; j += 256) bucket[e0 + j] = sb[j];
}

// ---------------- W convert: Wt[n][k] = bf16(W[k][n]) ----------------
__global__ __launch_bounds__(256) void convert_w(const float* __restrict__ W1,
                                                 const float* __restrict__ W2,
                                                 ushort* __restrict__ Wt1,
                                                 ushort* __restrict__ Wt2) {
    int idx = blockIdx.x * 256 + threadIdx.x;
    const float* W = (idx < 16384) ? W1 : W2;
    ushort* O = (idx < 16384) ? Wt1 : Wt2;
    int i = idx & 16383;
    int k = i >> 7, n = i & 127;
    O[n * 128 + k] = f2bf(W[i]);
}

// ---------------- MFMA GEMM + attention coefficients ----------------
// Block 64x128, 4 waves (2M x 2N). Input either f32 (layer 1) or bf16 (layer 2).
#define LDK 136
template <bool BF16IN>
__global__ __launch_bounds__(256) void gemm_attn_mfma(const void* __restrict__ in_,
                                                      const ushort* __restrict__ Wt,
                                                      const float* __restrict__ al,
                                                      const float* __restrict__ ar,
                                                      ushort* __restrict__ feat,
                                                      float* __restrict__ el,
                                                      float* __restrict__ er, int N) {
    __shared__ ushort sA[64 * LDK];
    int tid = threadIdx.x;
    int rowbase = blockIdx.x * 64;

    if (BF16IN) {
        const ushort* in = (const ushort*)in_;
#pragma unroll
        for (int i = 0; i < 4; ++i) {
            int idx8 = i * 256 + tid;  // ushort8 index
            int flat = idx8 * 8;
            int row = flat >> 7, col = flat & 127;
            int grow = rowbase + row;
            uint4 v = make_uint4(0, 0, 0, 0);
            if (grow < N) v = *reinterpret_cast<const uint4*>(in + (size_t)grow * 128 + col);
            *reinterpret_cast<uint4*>(&sA[row * LDK + col]) = v;
        }
    } else {
        const float* in = (const float*)in_;
#pragma unroll
        for (int i = 0; i < 8; ++i) {
            int idx4 = i * 256 + tid;
            int flat = idx4 * 4;
            int row = flat >> 7, col = flat & 127;
            int grow = rowbase + row;
            float4 v = make_float4(0.f, 0.f, 0.f, 0.f);
            if (grow < N) v = *reinterpret_cast<const float4*>(in + (size_t)grow * 128 + col);
            uint2 w;
            w.x = (unsigned int)f2bf(v.x) | ((unsigned int)f2bf(v.y) << 16);
            w.y = (unsigned int)f2bf(v.z) | ((unsigned int)f2bf(v.w) << 16);
            *reinterpret_cast<uint2*>(&sA[row * LDK + col]) = w;
        }
    }
    __syncthreads();

    int wid = tid >> 6;
    int lane = tid & 63;
    int wm = wid >> 1;
    int wn = wid & 1;
    int l15 = lane & 15;
    int lhi = lane >> 4;

    f32x4 acc[2][4] = {};
    const ushort* wb = Wt + (size_t)(wn * 64 + l15) * 128 + lhi * 8;
    const ushort* a0p = &sA[(wm * 32 + l15) * LDK + lhi * 8];
    const ushort* a1p = &sA[(wm * 32 + 16 + l15) * LDK + lhi * 8];

#pragma unroll
    for (int ks = 0; ks < 4; ++ks) {
        bf16x8 a0 = *reinterpret_cast<const bf16x8*>(a0p + ks * 32);
        bf16x8 a1 = *reinterpret_cast<const bf16x8*>(a1p + ks * 32);
#pragma unroll
        for (int ni = 0; ni < 4; ++ni) {
            bf16x8 b = *reinterpret_cast<const bf16x8*>(wb + ni * 16 * 128 + ks * 32);
            acc[0][ni] = __builtin_amdgcn_mfma_f32_16x16x32_bf16(a0, b, acc[0][ni], 0, 0, 0);
            acc[1][ni] = __builtin_amdgcn_mfma_f32_16x16x32_bf16(a1, b, acc[1][ni], 0, 0, 0);
        }
    }

#pragma unroll
    for (int ni = 0; ni < 4; ++ni) {
        int head = wn * 4 + ni;
        float alv = al[head * 16 + l15];
        float arv = ar[head * 16 + l15];
#pragma unroll
        for (int mi = 0; mi < 2; ++mi) {
#pragma unroll
            for (int reg = 0; reg < 4; ++reg) {
                int row = rowbase + wm * 32 + mi * 16 + lhi * 4 + reg;
                float v = acc[mi][ni][reg];
                float pl = v * alv;
                float pr = v * arv;
#pragma unroll
                for (int off = 8; off; off >>= 1) {
                    pl += __shfl_xor(pl, off);
                    pr += __shfl_xor(pr, off);
                }
                if (row < N) {
                    feat[(size_t)row * 128 + head * 16 + l15] = f2bf(v);
                    if (l15 == 0) {
                        el[row * 8 + head] = pl;
                        er[row * 8 + head] = pr;
                    }
                }
            }
        }
    }
}

// ---------------- per-dst-node softmax + aggregation ----------------
// One wave per node. Two-phase batch-8:
//   phase 1: 64 lanes = 8 edges x 8 heads -> ONE exp per (edge,head) (8x fewer
//            than the per-lane-redundant version); denominator accumulates
//            per-lane, reduced once at the end via 3 shfl_xor.
//   phase 2: per edge, redistribute p via shfl; lane does its 2-component FMA.
// Output bf16 (consumer converts to bf16 anyway -> no extra precision loss).
__global__ __launch_bounds__(256) void aggregate(const ushort* __restrict__ feat,
                                                 const float* __restrict__ el,
                                                 const float* __restrict__ er,
                                                 const int* __restrict__ rowstart,
                                                 const ushort* __restrict__ bucket,
                                                 const float* __restrict__ bias,
                                                 ushort* __restrict__ out,
                                                 int N, int do_relu) {
    int wid = (blockIdx.x * 256 + threadIdx.x) >> 6;
    int lane = threadIdx.x & 63;
    if (wid >= N) return;
    int l7 = lane & 7;    // phase-1 head
    int e8 = lane >> 3;   // phase-1 edge slot; also phase-2 head
    float erv = er[wid * 8 + l7];
    int beg = rowstart[wid];
    int end = rowstart[wid + 1];

    const unsigned int* fp = reinterpret_cast<const unsigned int*>(feat) + lane;

    float lsum = 0.0f, ax = 0.0f, ay = 0.0f;

    for (int base = beg; base < end; base += 64) {
        int cnt = min(end - base, 64);
        int myedge = base + lane;
        int sv64 = ((myedge < end) ? (int)bucket[myedge] : 0) << 6;  // s*64 (uint index)

        int k = 0;
        for (; k + 8 <= cnt; k += 8) {
            // phase 1: edge k+e8, head l7
            int se = __shfl(sv64, k + e8);
            float e = el[(se >> 3) + l7] + erv;
            e = (e > 0.0f) ? e : LEAKY * e;
            float p = __expf(e);
            lsum += p;
            // phase 2: 8 edges, unguarded
#pragma unroll
            for (int q = 0; q < 8; ++q) {
                int su = __shfl(sv64, k + q);
                float pq = __shfl(p, q * 8 + e8);
                unsigned int u = fp[su];
                ax = fmaf(pq, __uint_as_float(u << 16), ax);
                ay = fmaf(pq, __uint_as_float(u & 0xffff0000u), ay);
            }
        }
        if (k < cnt) {  // tail batch, wave-uniform guards
            int se = __shfl(sv64, min(k + e8, cnt - 1));
            bool valid = (k + e8) < cnt;
            float e = el[(se >> 3) + l7] + erv;
            e = (e > 0.0f) ? e : LEAKY * e;
            float p = valid ? __expf(e) : 0.0f;
            lsum += p;
#pragma unroll
            for (int q = 0; q < 8; ++q) {
                if (k + q < cnt) {
                    int su = __shfl(sv64, k + q);
                    float pq = __shfl(p, q * 8 + e8);
                    unsigned int u = fp[su];
                    ax = fmaf(pq, __uint_as_float(u << 16), ax);
                    ay = fmaf(pq, __uint_as_float(u & 0xffff0000u), ay);
                }
            }
        }
    }

    // denominator: sum lsum over lanes with same l7 (xor-group {8,16,32})
    lsum += __shfl_xor(lsum, 8);
    lsum += __shfl_xor(lsum, 16);
    lsum += __shfl_xor(lsum, 32);
    float denom = __shfl(lsum, e8);  // lane e8 (<8) holds head e8's denom
    float inv = (end > beg) ? 1.0f / denom : 0.0f;

    int c = lane * 2;
    float2 bv = *reinterpret_cast<const float2*>(bias + c);
    float ox = fmaf(ax, inv, bv.x);
    float oy = fmaf(ay, inv, bv.y);
    if (do_relu) {
        ox = fmaxf(ox, 0.0f);
        oy = fmaxf(oy, 0.0f);
    }
    unsigned int pk = (unsigned int)f2bf(ox) | ((unsigned int)f2bf(oy) << 16);
    reinterpret_cast<unsigned int*>(out)[(size_t)wid * 64 + lane] = pk;
}

// ---------------- readout ----------------
__global__ __launch_bounds__(256) void mean_reduce(const ushort* __restrict__ h,
                                                   float* __restrict__ meanbuf, int N) {
    int c = threadIdx.x & 127;
    int rbase = blockIdx.x * 2 + (threadIdx.x >> 7);
    float s = 0.0f;
    for (int r = rbase; r < N; r += gridDim.x * 2)
        s += __uint_as_float((unsigned int)h[(size_t)r * 128 + c] << 16);
    atomicAdd(&meanbuf[c], s);
}

__global__ __launch_bounds__(64) void classifier(const float* __restrict__ meanbuf,
                                                 const float* __restrict__ Wc,
                                                 const float* __restrict__ bc,
                                                 float* __restrict__ outp, float invN) {
    int j = threadIdx.x;
    if (j < 10) {
        float s = 0.0f;
        for (int k = 0; k < 128; ++k) s += meanbuf[k] * invN * Wc[k * 10 + j];
        outp[j] = s + bc[j];
    }
}

// ---------------- launch ----------------

extern "C" void kernel_launch(void* const* d_in, const int* in_sizes, int n_in,
                              void* d_out, int out_size, void* d_ws, size_t ws_size,
                              hipStream_t stream) {
    const float* x   = (const float*)d_in[0];
    const int*   src = (const int*)d_in[1];
    const int*   dst = (const int*)d_in[2];
    const float* W1  = (const float*)d_in[3];
    const float* al1 = (const float*)d_in[4];
    const float* ar1 = (const float*)d_in[5];
    const float* b1  = (const float*)d_in[6];
    const float* W2  = (const float*)d_in[7];
    const float* al2 = (const float*)d_in[8];
    const float* ar2 = (const float*)d_in[9];
    const float* b2  = (const float*)d_in[10];
    const float* Wc  = (const float*)d_in[11];
    const float* bc  = (const float*)d_in[12];

    int N = in_sizes[0] / 128;
    int E = in_sizes[1];
    int NB = (N + (1 << BINB) - 1) >> BINB;

    size_t off = 0;
    auto alloc = [&](size_t bytes) -> void* {
        void* p = (char*)d_ws + off;
        off += (bytes + 255) & ~size_t(255);
        return p;
    };
    int*   bin_cnt    = (int*)alloc(sizeof(int) * NB);
    int*   binStart   = (int*)alloc(sizeof(int) * (NB + 1));
    int*   bin_cursor = (int*)alloc(sizeof(int) * NB);
    int*   rowstart   = (int*)alloc(sizeof(int) * (N + 1));
    unsigned int* coarse = (unsigned int*)alloc(sizeof(unsigned int) * E);
    ushort* bucket  = (ushort*)alloc(sizeof(ushort) * E);
    ushort* feat    = (ushort*)alloc(sizeof(ushort) * (size_t)N * 128);
    float* el       = (float*)alloc(sizeof(float) * N * 8);
    float* er       = (float*)alloc(sizeof(float) * N * 8);
    ushort* h1      = (ushort*)alloc(sizeof(ushort) * (size_t)N * 128);
    ushort* h2      = (ushort*)alloc(sizeof(ushort) * (size_t)N * 128);
    float* meanbuf  = (float*)alloc(sizeof(float) * 128);
    ushort* Wt1     = (ushort*)alloc(sizeof(ushort) * 128 * 128);
    ushort* Wt2     = (ushort*)alloc(sizeof(ushort) * 128 * 128);

    hipMemsetAsync(bin_cnt, 0, sizeof(int) * NB, stream);
    hipMemsetAsync(meanbuf, 0, sizeof(float) * 128, stream);

    int GB = ceil_div(E, TILE);

    bin_count<<<GB, 256, 0, stream>>>(dst, bin_cnt, E, NB);
    bin_scan<<<1, 256, 0, stream>>>(bin_cnt, binStart, bin_cursor, rowstart, NB, N, E);
    bin_scatter<<<GB, 256, 0, stream>>>(src, dst, bin_cursor, coarse, E);
    fine_csr<<<NB, 256, 0, stream>>>(coarse, binStart, rowstart, bucket, N);
    convert_w<<<128, 256, 0, stream>>>(W1, W2, Wt1, Wt2);

    // layer 1 (f32 input)
    gemm_attn_mfma<false><<<ceil_div(N, 64), 256, 0, stream>>>(x, Wt1, al1, ar1, feat, el, er, N);
    aggregate<<<ceil_div(N * 64, 256), 256, 0, stream>>>(feat, el, er, rowstart, bucket, b1, h1, N, 1);
    // layer 2 (bf16 input)
    gemm_attn_mfma<true><<<ceil_div(N, 64), 256, 0, stream>>>(h1, Wt2, al2, ar2, feat, el, er, N);
    aggregate<<<ceil_div(N * 64, 256), 256, 0, stream>>>(feat, el, er, rowstart, bucket, b2, h2, N, 0);
    // readout
    mean_reduce<<<256, 256, 0, stream>>>(h2, meanbuf, N);
    classifier<<<1, 64, 0, stream>>>(meanbuf, Wc, bc, (float*)d_out, 1.0f / (float)N);
}